// Round 10
// baseline (1633.932 us; speedup 1.0000x reference)
//
#include <hip/hip_runtime.h>
#include <math.h>

// TfLSTM: x[512,256,128] -> LSTM(100, relu) -> LSTM(128, relu, last) -> Dense(19) -> softmax
// Round 15: rec1 weights moved to LDS. r5-r12 evidence: the allocator never
// holds >~130-236 regs across a barrier loop (remat/AGPR-split every time) ->
// per-step pinned ~2330cy by L2 reloads. New rec1: U1 staged once into
// 160,016 B dynamic LDS as [col][k] stride 100; per-step reads ds_read_b128;
// unique bank-work ~41.6K dwords/step ≈ 1300-1900 cy for TWO batch rows
// (rows adjacent in-wave -> weight reads broadcast, free). Thread
// (cl,ks,row): unit cl, k-half ks (0..51 / 52..103, hs pad 100..103 = 0
// nullifies the 4-dword col overrun), row. ks-reduce = 1 shfl_xor(2); all 4
// gates in-thread -> c-update in-thread; 1 barrier/step (hs double-buffer).
// Grid 256 = one round, every CU busy. VGPR ~60-100 -> no remat possible.
//   ws layout (floats): zxbuf 209.7MB | h1seq 52.4MB | cbuf/hbuf/h2buf 0.26MB ea.

#define T_SEQ 256
#define BATCH 512
#define IN_DIM 128
#define H1 100
#define H2 128
#define NCLS 19

typedef float f4v __attribute__((ext_vector_type(4)));

__device__ __forceinline__ float sigmoidf_(float x) {
    return 1.0f / (1.0f + __expf(-x));
}
__device__ __forceinline__ float hsum4_(f4v v) {
    return (v.x + v.y) + (v.z + v.w);
}

#define REP8(M)  M(0) M(1) M(2) M(3) M(4) M(5) M(6) M(7)
#define REP13(M) M(0) M(1) M(2) M(3) M(4) M(5) M(6) M(7) M(8) M(9) M(10) M(11) M(12)

// =================== projection GEMM (r14) ===================
template<int K, int N, bool SWAP>
__global__ __launch_bounds__(256, 2)
void proj_kernel(const float* __restrict__ A, const float* __restrict__ W,
                 const float* __restrict__ bias, float* __restrict__ out)
{
    constexpr int LDA = 132;  // As row stride
    constexpr int WCG = 260;  // Ws colgroup stride (32*8 + 4)
    __shared__ __align__(16) float As[32 * LDA];   // 16.9 KB
    __shared__ __align__(16) float Ws[16 * WCG];   // 16.6 KB
    const int tid = threadIdx.x;
    const int r0 = blockIdx.x * 128;
    const int c0 = blockIdx.y * 128;
    const int ty = tid >> 4, tx = tid & 15;

#define PACC(i) f4v accL##i = {0.f,0.f,0.f,0.f}; f4v accR##i = {0.f,0.f,0.f,0.f};
    REP8(PACC)
#undef PACC

    for (int kk = 0; kk < K; kk += 32) {
        __syncthreads();
        // stage A chunk transposed: As[k][row]
#pragma unroll
        for (int i = 0; i < 4; ++i) {
            int idx = tid + i * 256;          // 1024 float4 slots: 128 rows x 8 kgroups
            int row = idx >> 3, kg = idx & 7;
            int k = kk + kg * 4;
            f4v v = {0.f, 0.f, 0.f, 0.f};
            if (k < K) v = *(const f4v*)&A[(size_t)(r0 + row) * K + k];
            As[(kg * 4 + 0) * LDA + row] = v.x;
            As[(kg * 4 + 1) * LDA + row] = v.y;
            As[(kg * 4 + 2) * LDA + row] = v.z;
            As[(kg * 4 + 3) * LDA + row] = v.w;
        }
        // stage W chunk: Ws[cg][k*8 + half*4]
#pragma unroll
        for (int i = 0; i < 4; ++i) {
            int idx = tid + i * 256;          // 1024 float4 slots: 32 k x 32 colquads
            int k = idx >> 5, q = idx & 31;
            int gk = kk + k, gc = c0 + q * 4;
            f4v v = {0.f, 0.f, 0.f, 0.f};
            if (gk < K && gc < N) v = *(const f4v*)&W[(size_t)gk * N + gc];
            int cg = q >> 1, half = q & 1;
            *(f4v*)&Ws[cg * WCG + k * 8 + half * 4] = v;
        }
        __syncthreads();
#pragma unroll
        for (int k = 0; k < 32; ++k) {
            f4v av0 = *(const f4v*)&As[k * LDA + ty * 8];
            f4v av1 = *(const f4v*)&As[k * LDA + ty * 8 + 4];
            f4v b0v = *(const f4v*)&Ws[tx * WCG + k * 8];
            f4v b1v = *(const f4v*)&Ws[tx * WCG + k * 8 + 4];
#define PFMA(i, s) accL##i += (s) * b0v; accR##i += (s) * b1v;
            PFMA(0, av0.x) PFMA(1, av0.y) PFMA(2, av0.z) PFMA(3, av0.w)
            PFMA(4, av1.x) PFMA(5, av1.y) PFMA(6, av1.z) PFMA(7, av1.w)
#undef PFMA
        }
    }

    // epilogue: + bias, guarded f4 stores
    const int cb = c0 + tx * 8;
    float b0 = (cb + 0 < N) ? bias[cb + 0] : 0.f;
    float b1 = (cb + 1 < N) ? bias[cb + 1] : 0.f;
    float b2 = (cb + 2 < N) ? bias[cb + 2] : 0.f;
    float b3 = (cb + 3 < N) ? bias[cb + 3] : 0.f;
    float b4 = (cb + 4 < N) ? bias[cb + 4] : 0.f;
    float b5 = (cb + 5 < N) ? bias[cb + 5] : 0.f;
    float b6 = (cb + 6 < N) ? bias[cb + 6] : 0.f;
    float b7 = (cb + 7 < N) ? bias[cb + 7] : 0.f;
    f4v bL = {b0, b1, b2, b3};
    f4v bR = {b4, b5, b6, b7};
#define PST(i) { \
        int r = r0 + ty * 8 + i; \
        size_t orow = SWAP ? ((size_t)(r & 255) * BATCH + (r >> 8)) : (size_t)r; \
        if (cb < N)     { f4v v = accL##i + bL; *(f4v*)&out[orow * N + cb] = v; } \
        if (cb + 4 < N) { f4v v = accR##i + bR; *(f4v*)&out[orow * N + cb + 4] = v; } }
    REP8(PST)
#undef PST
}

// =================== recurrence, layer 1 (LDS-weight, 2 rows/block) ===================
// U1 in dynamic LDS [col][k] stride 100 dwords (40,004 dwords incl. 4-dword
// overrun pad). Thread tid = cl*4 + ks*2 + row: unit cl (0..127, active
// <100), k-half ks, batch row. The 2 row-lanes of a (cl,ks) read identical
// weight addresses -> same-wave broadcast (free). ks=0 covers k 0..51,
// ks=1 k 52..103 (hs pad zeros nullify k>=100 terms and the col overrun).
// ks-reduce: shfl_xor(2). All 4 gates per thread -> c-update in-thread
// (both ks lanes redundantly; ks==0 stores). One barrier/step.
__global__ __launch_bounds__(512, 1)
void rec1_kernel(const float* __restrict__ zx,   // [T][B][400]
                 const float* __restrict__ U1,   // [100][400]
                 float* __restrict__ h1seq)      // [T][B][100]
{
    extern __shared__ float Wl[];                  // 40,004 dwords = 160,016 B
    __shared__ __align__(16) float hs2[2][2][104]; // [buf][row][unit], pad = 0
    const int tid = threadIdx.x;
    const int row = tid & 1;
    const int ks  = (tid >> 1) & 1;
    const int cl  = tid >> 2;            // 0..127, active < 100
    const bool act = (cl < H1);
    const int cc  = act ? cl : 0;
    const int brow = blockIdx.x * 2 + row;
    const int k0 = ks * 52;              // ks=0: k 0..51; ks=1: k 52..103

    // stage U1 -> LDS transposed (global reads coalesced over columns)
    for (int k = 0; k < H1; ++k) {
        if (tid < 400) Wl[tid * 100 + k] = U1[(size_t)k * 400 + tid];
    }
    {   // zero hs (both buffers, both rows, incl. pad 100..103)
        float* h4 = &hs2[0][0][0];
        if (tid < 416) h4[tid] = 0.0f;
    }
    const int wc0 = (0 * 100 + cc) * 100;
    const int wc1 = (1 * 100 + cc) * 100;
    const int wc2 = (2 * 100 + cc) * 100;
    const int wc3 = (3 * 100 + cc) * 100;

    float cst = 0.0f;
    const float* pz0 = zx + (size_t)brow * 400 + cc;
    float zc0 = pz0[0], zc1 = pz0[100], zc2 = pz0[200], zc3 = pz0[300];
    __syncthreads();

    for (int t = 0; t < T_SEQ; ++t) {
        // prefetch next step's zx (in flight under the LDS/FMA phase)
        int tn = (t + 1 < T_SEQ) ? t + 1 : t;
        const float* pz = zx + ((size_t)tn * BATCH + brow) * 400 + cc;
        float zn0 = pz[0], zn1 = pz[100], zn2 = pz[200], zn3 = pz[300];

        float a0 = 0.f, a1 = 0.f, a2 = 0.f, a3 = 0.f;
        if (act) {   // masked off for cl>=100: saves 22% LDS bank-work
            const float* hb = &hs2[t & 1][row][0];
            f4v s0 = {0.f,0.f,0.f,0.f};
            f4v s1 = {0.f,0.f,0.f,0.f};
            f4v s2 = {0.f,0.f,0.f,0.f};
            f4v s3 = {0.f,0.f,0.f,0.f};
#define R1F(j) { f4v hv = *(const f4v*)&hb[k0 + 4*(j)]; \
            s0 += hv * *(const f4v*)&Wl[wc0 + k0 + 4*(j)]; \
            s1 += hv * *(const f4v*)&Wl[wc1 + k0 + 4*(j)]; \
            s2 += hv * *(const f4v*)&Wl[wc2 + k0 + 4*(j)]; \
            s3 += hv * *(const f4v*)&Wl[wc3 + k0 + 4*(j)]; }
            REP13(R1F)
#undef R1F
            a0 = hsum4_(s0); a1 = hsum4_(s1); a2 = hsum4_(s2); a3 = hsum4_(s3);
            // ks-reduce: partner lane = lane^2 (same cl, other k-half)
            a0 += __shfl_xor(a0, 2, 64);
            a1 += __shfl_xor(a1, 2, 64);
            a2 += __shfl_xor(a2, 2, 64);
            a3 += __shfl_xor(a3, 2, 64);

            float iv = sigmoidf_(zc0 + a0);            // gate order i, f, g, o
            float fv = sigmoidf_(zc1 + a1);
            float gv = fmaxf(zc2 + a2, 0.0f);          // candidate: relu
            float ov = sigmoidf_(zc3 + a3);
            cst = fv * cst + iv * gv;                  // c = f*c + i*g
            float h = ov * fmaxf(cst, 0.0f);           // h = o*relu(c)
            if (ks == 0) {
                hs2[(t + 1) & 1][row][cl] = h;         // write NEXT buffer
                h1seq[((size_t)t * BATCH + brow) * H1 + cl] = h;
            }
        }
        __syncthreads();
        zc0 = zn0; zc1 = zn1; zc2 = zn2; zc3 = zn3;
    }
}

// =================== recurrence, layer 2 (time-chunked) ===================
template<bool INIT, bool LAST>
__global__ __launch_bounds__(512)
__attribute__((amdgpu_waves_per_eu(2, 2)))
void rec2_chunk(const float* __restrict__ zx,    // [tlen][B][512] (bias included)
                const float* __restrict__ U2,    // [128][512]
                float* __restrict__ cbuf,        // [B][128]
                float* __restrict__ hbuf,        // [B][128]
                float* __restrict__ h2out,       // [B][128] (used when LAST)
                int tlen)
{
    const int row = blockIdx.x;
    const int tid = threadIdx.x;   // 0..511
    const int kq = tid >> 7;
    const int cl = tid & 127;
    __shared__ __align__(16) float hs[H2];
    __shared__ float zp[4 * 512];
    __shared__ float za[512];

#define R2_LD(j) \
    f4v w0_##j, w1_##j, w2_##j, w3_##j; { \
        const float* p = U2 + (size_t)(kq * 32 + 4 * j) * 512 + cl; \
        w0_##j = (f4v){p[0],   p[512],       p[1024],       p[1536]}; \
        w1_##j = (f4v){p[128], p[512 + 128], p[1024 + 128], p[1536 + 128]}; \
        w2_##j = (f4v){p[256], p[512 + 256], p[1024 + 256], p[1536 + 256]}; \
        w3_##j = (f4v){p[384], p[512 + 384], p[1024 + 384], p[1536 + 384]}; }
    REP8(R2_LD)
#undef R2_LD
    // pin weights (r10: harmless here, keeps the gather rooted)
#define R2P(j) asm volatile("" : "+v"(w0_##j), "+v"(w1_##j), "+v"(w2_##j), "+v"(w3_##j));
    REP8(R2P)
#undef R2P

    float cst = 0.0f;
    if (tid < H2) {
        if (INIT) {
            hs[tid] = 0.0f;
        } else {
            hs[tid] = hbuf[(size_t)row * H2 + tid];
            cst = cbuf[(size_t)row * H2 + tid];
        }
    }
    float zc = zx[(size_t)row * 512 + tid];
    __syncthreads();

    for (int t = 0; t < tlen; ++t) {
        int tn = (t + 1 < tlen) ? t + 1 : t;
        float zn = zx[((size_t)tn * BATCH + row) * 512 + tid];

        f4v s0 = {0.f, 0.f, 0.f, 0.f};
        f4v s1 = {0.f, 0.f, 0.f, 0.f};
        f4v s2 = {0.f, 0.f, 0.f, 0.f};
        f4v s3 = {0.f, 0.f, 0.f, 0.f};
#define R2_FMA(j) { f4v hv = *(const f4v*)&hs[kq * 32 + 4 * j]; \
        s0 += hv * w0_##j; s1 += hv * w1_##j; s2 += hv * w2_##j; s3 += hv * w3_##j; }
        REP8(R2_FMA)
#undef R2_FMA
        zp[kq * 512 + cl]       = hsum4_(s0);
        zp[kq * 512 + cl + 128] = hsum4_(s1);
        zp[kq * 512 + cl + 256] = hsum4_(s2);
        zp[kq * 512 + cl + 384] = hsum4_(s3);
        __syncthreads();

        float z = zc + (zp[tid] + zp[512 + tid]) + (zp[1024 + tid] + zp[1536 + tid]);
        float a = (tid >= 2 * H2 && tid < 3 * H2) ? fmaxf(z, 0.0f) : sigmoidf_(z);
        za[tid] = a;
        __syncthreads();

        if (tid < H2) {
            float i = za[tid], f = za[tid + 128], g = za[tid + 256], o = za[tid + 384];
            cst = f * cst + i * g;
            hs[tid] = o * fmaxf(cst, 0.0f);
        }
        __syncthreads();
        zc = zn;
    }

    if (tid < H2) {
        float h = hs[tid];
        cbuf[(size_t)row * H2 + tid] = cst;
        hbuf[(size_t)row * H2 + tid] = h;
        if (LAST) h2out[(size_t)row * H2 + tid] = h;
    }
}

// =================== dense + softmax ===================
__global__ __launch_bounds__(64, 1)
void dense_softmax_kernel(const float* __restrict__ h2, const float* __restrict__ Wd,
                          const float* __restrict__ bd, float* __restrict__ out)
{
    const int b = blockIdx.x;
    const int k = threadIdx.x;
    __shared__ __align__(16) float hsm[H2];
    if (k < H2 / 4) ((f4v*)hsm)[k] = ((const f4v*)(h2 + (size_t)b * H2))[k];
    __syncthreads();

    float logit = -1e30f;
    if (k < NCLS) {
        float acc = bd[k];
#pragma unroll
        for (int d = 0; d < H2; ++d) acc += hsm[d] * Wd[d * NCLS + k];
        logit = acc;
    }
    float m = logit;
#pragma unroll
    for (int off = 32; off >= 1; off >>= 1) m = fmaxf(m, __shfl_xor(m, off, 64));
    float e = (k < NCLS) ? __expf(logit - m) : 0.0f;
    float s = e;
#pragma unroll
    for (int off = 32; off >= 1; off >>= 1) s += __shfl_xor(s, off, 64);
    if (k < NCLS) out[(size_t)b * NCLS + k] = e / s;
}

// =================== fallback (round-1) kernels ===================
__global__ __launch_bounds__(448, 1)
void lstm1_fb(const float* __restrict__ x, const float* __restrict__ W1,
              const float* __restrict__ U1, const float* __restrict__ b1,
              float* __restrict__ h1out)
{
    const int b = blockIdx.x;
    const int k = threadIdx.x;
    __shared__ __align__(16) float xs[IN_DIM];
    __shared__ __align__(16) float hs[H1];
    __shared__ __align__(16) float zs[4 * H1];
    float w1r[IN_DIM];
    float u1r[H1];
    float bias = 0.0f;
    if (k < 4 * H1) {
        bias = b1[k];
#pragma unroll
        for (int d = 0; d < IN_DIM; ++d) w1r[d] = W1[d * (4 * H1) + k];
#pragma unroll
        for (int j = 0; j < H1; ++j) u1r[j] = U1[j * (4 * H1) + k];
    }
    if (k < H1) hs[k] = 0.0f;
    if (k < IN_DIM / 4)
        ((float4*)xs)[k] = ((const float4*)(x + ((size_t)b * T_SEQ) * IN_DIM))[k];
    float c = 0.0f;
    __syncthreads();
    for (int t = 0; t < T_SEQ; ++t) {
        if (k < 4 * H1) {
            float acc0 = bias, acc1 = 0.f, acc2 = 0.f, acc3 = 0.f;
#pragma unroll
            for (int q = 0; q < IN_DIM / 4; ++q) {
                float4 xv = ((const float4*)xs)[q];
                acc0 += xv.x * w1r[4 * q]; acc1 += xv.y * w1r[4 * q + 1];
                acc2 += xv.z * w1r[4 * q + 2]; acc3 += xv.w * w1r[4 * q + 3];
            }
#pragma unroll
            for (int q = 0; q < H1 / 4; ++q) {
                float4 hv = ((const float4*)hs)[q];
                acc0 += hv.x * u1r[4 * q]; acc1 += hv.y * u1r[4 * q + 1];
                acc2 += hv.z * u1r[4 * q + 2]; acc3 += hv.w * u1r[4 * q + 3];
            }
            float zv = (acc0 + acc1) + (acc2 + acc3);
            zs[k] = (k >= 2 * H1 && k < 3 * H1) ? fmaxf(zv, 0.0f) : sigmoidf_(zv);
        }
        __syncthreads();
        if (k < H1) {
            float i = zs[k], f = zs[k + H1], g = zs[k + 2 * H1], o = zs[k + 3 * H1];
            c = f * c + i * g;
            float h = o * fmaxf(c, 0.0f);
            hs[k] = h;
            h1out[((size_t)t * BATCH + b) * H1 + k] = h;
        }
        int tn = t + 1;
        if (tn < T_SEQ && k < IN_DIM / 4)
            ((float4*)xs)[k] = ((const float4*)(x + ((size_t)b * T_SEQ + tn) * IN_DIM))[k];
        __syncthreads();
    }
}

__global__ __launch_bounds__(512, 1)
void lstm2_fb(const float* __restrict__ h1in, const float* __restrict__ W2,
              const float* __restrict__ U2, const float* __restrict__ b2,
              float* __restrict__ h2out)
{
    const int b = blockIdx.x;
    const int k = threadIdx.x;
    __shared__ __align__(16) float ps[H1];
    __shared__ __align__(16) float hs[H2];
    __shared__ __align__(16) float zs[4 * H2];
    float w2r[H1];
    float u2r[H2];
    float bias = b2[k];
#pragma unroll
    for (int j = 0; j < H1; ++j) w2r[j] = W2[j * (4 * H2) + k];
#pragma unroll
    for (int j = 0; j < H2; ++j) u2r[j] = U2[j * (4 * H2) + k];
    if (k < H2) hs[k] = 0.0f;
    if (k < H1 / 4)
        ((float4*)ps)[k] = ((const float4*)(h1in + (size_t)b * H1))[k];
    float c = 0.0f;
    float hlast = 0.0f;
    __syncthreads();
    for (int t = 0; t < T_SEQ; ++t) {
        float acc0 = bias, acc1 = 0.f, acc2 = 0.f, acc3 = 0.f;
#pragma unroll
        for (int q = 0; q < H1 / 4; ++q) {
            float4 pv = ((const float4*)ps)[q];
            acc0 += pv.x * w2r[4 * q]; acc1 += pv.y * w2r[4 * q + 1];
            acc2 += pv.z * w2r[4 * q + 2]; acc3 += pv.w * w2r[4 * q + 3];
        }
#pragma unroll
        for (int q = 0; q < H2 / 4; ++q) {
            float4 hv = ((const float4*)hs)[q];
            acc0 += hv.x * u2r[4 * q]; acc1 += hv.y * u2r[4 * q + 1];
            acc2 += hv.z * u2r[4 * q + 2]; acc3 += hv.w * u2r[4 * q + 3];
        }
        float zv = (acc0 + acc1) + (acc2 + acc3);
        zs[k] = (k >= 2 * H2 && k < 3 * H2) ? fmaxf(zv, 0.0f) : sigmoidf_(zv);
        __syncthreads();
        if (k < H2) {
            float i = zs[k], f = zs[k + H2], g = zs[k + 2 * H2], o = zs[k + 3 * H2];
            c = f * c + i * g;
            hlast = o * fmaxf(c, 0.0f);
            hs[k] = hlast;
        }
        int tn = t + 1;
        if (tn < T_SEQ && k < H1 / 4)
            ((float4*)ps)[k] = ((const float4*)(h1in + ((size_t)tn * BATCH + b) * H1))[k];
        __syncthreads();
    }
    if (k < H2) h2out[(size_t)b * H2 + k] = hlast;
}

extern "C" void kernel_launch(void* const* d_in, const int* in_sizes, int n_in,
                              void* d_out, int out_size, void* d_ws, size_t ws_size,
                              hipStream_t stream) {
    const float* x  = (const float*)d_in[0];
    const float* W1 = (const float*)d_in[1];
    const float* U1 = (const float*)d_in[2];
    const float* b1 = (const float*)d_in[3];
    const float* W2 = (const float*)d_in[4];
    const float* U2 = (const float*)d_in[5];
    const float* b2 = (const float*)d_in[6];
    const float* Wd = (const float*)d_in[7];
    const float* bd = (const float*)d_in[8];
    float* out = (float*)d_out;

    const size_t zx_elems = (size_t)T_SEQ * BATCH * 400;   // 52428800
    const size_t h1_elems = (size_t)T_SEQ * BATCH * H1;    // 13107200
    const size_t st_elems = (size_t)BATCH * H2;            // 65536
    const size_t need = (zx_elems + h1_elems + 3 * st_elems) * sizeof(float);  // 262.93 MB

    if (ws_size >= need) {
        float* zxbuf = (float*)d_ws;
        float* h1buf = zxbuf + zx_elems;
        float* cbuf  = h1buf + h1_elems;
        float* hbuf  = cbuf + st_elems;
        float* h2buf = hbuf + st_elems;
        const int TC = T_SEQ / 2;   // 128-step chunks

        // zx1 = x @ W1 + b1 -> [T][B][400]
        hipLaunchKernelGGL((proj_kernel<IN_DIM, 4 * H1, true>), dim3(1024, 4), dim3(256), 0, stream,
                           x, W1, b1, zxbuf);
        // rec1: dynamic LDS = 40,004 dwords (U1 transposed + 4-dword overrun pad)
        hipLaunchKernelGGL(rec1_kernel, dim3(BATCH / 2), dim3(512), 40004 * sizeof(float), stream,
                           zxbuf, U1, h1buf);
        // ---- layer 2, chunk A (t = 0..127): zx2 chunk overwrites zx1 region ----
        hipLaunchKernelGGL((proj_kernel<H1, 4 * H2, false>), dim3(512, 4), dim3(256), 0, stream,
                           h1buf, W2, b2, zxbuf);
        hipLaunchKernelGGL((rec2_chunk<true, false>), dim3(BATCH), dim3(512), 0, stream,
                           zxbuf, U2, cbuf, hbuf, h2buf, TC);
        // ---- layer 2, chunk B (t = 128..255) ----
        hipLaunchKernelGGL((proj_kernel<H1, 4 * H2, false>), dim3(512, 4), dim3(256), 0, stream,
                           h1buf + (size_t)TC * BATCH * H1, W2, b2, zxbuf);
        hipLaunchKernelGGL((rec2_chunk<false, true>), dim3(BATCH), dim3(512), 0, stream,
                           zxbuf, U2, cbuf, hbuf, h2buf, TC);

        hipLaunchKernelGGL(dense_softmax_kernel, dim3(BATCH), dim3(64), 0, stream,
                           h2buf, Wd, bd, out);
    } else {
        // fallback: round-1 fused kernels (needs ~52.7 MB)
        float* h1buf = (float*)d_ws;
        float* h2buf = h1buf + h1_elems;
        hipLaunchKernelGGL(lstm1_fb, dim3(BATCH), dim3(448), 0, stream, x, W1, U1, b1, h1buf);
        hipLaunchKernelGGL(lstm2_fb, dim3(BATCH), dim3(512), 0, stream, h1buf, W2, U2, b2, h2buf);
        hipLaunchKernelGGL(dense_softmax_kernel, dim3(BATCH), dim3(64), 0, stream, h2buf, Wd, bd, out);
    }
}

// Round 11
// 1309.251 us; speedup vs baseline: 1.2480x; 1.2480x over previous
//
#include <hip/hip_runtime.h>
#include <math.h>

// TfLSTM: x[512,256,128] -> LSTM(100, relu) -> LSTM(128, relu, last) -> Dense(19) -> softmax
// Round 16: restore best-known rec1 (r10: 4-way ksplit + one-time asm pin,
// 460us measured) and cut rec2 from 3 to 2 barriers/step (drop the za LDS
// round-trip: tid<128 reads its 16 zp partials + own 4 zx cols and computes
// all gates in-thread; hs write after barrier#1 is safe since all FMA hs-reads
// precede zp writes).
// CLOSED BRANCHES (do not revisit):
//  - LDS-weights rec1 (r15): col-stride bank aliasing + >=2 phases x 520
//    ds_read/step -> floor ~560us > r10's 460us. SQ_LDS_BANK_CONFLICT 1.78e8.
//  - allocator register path: holds ~budget/2 loop-invariants at every
//    waves_per_eu tried (r5-r12); per-step pinned ~2160cy.
//  - proj dbuf w/ lambda-captured reg arrays (r13): scratch spill, 6.8GB writes.
//   ws layout (floats): zxbuf 209.7MB | h1seq 52.4MB | cbuf/hbuf/h2buf 0.26MB ea.

#define T_SEQ 256
#define BATCH 512
#define IN_DIM 128
#define H1 100
#define H2 128
#define NCLS 19

typedef float f4v __attribute__((ext_vector_type(4)));

__device__ __forceinline__ float sigmoidf_(float x) {
    return 1.0f / (1.0f + __expf(-x));
}
__device__ __forceinline__ float hsum4_(f4v v) {
    return (v.x + v.y) + (v.z + v.w);
}

#define REP4(M)  M(0) M(1) M(2) M(3)
#define REP7(M)  M(0) M(1) M(2) M(3) M(4) M(5) M(6)
#define REP8(M)  M(0) M(1) M(2) M(3) M(4) M(5) M(6) M(7)

// =================== projection GEMM (r14) ===================
template<int K, int N, bool SWAP>
__global__ __launch_bounds__(256, 2)
void proj_kernel(const float* __restrict__ A, const float* __restrict__ W,
                 const float* __restrict__ bias, float* __restrict__ out)
{
    constexpr int LDA = 132;  // As row stride
    constexpr int WCG = 260;  // Ws colgroup stride (32*8 + 4)
    __shared__ __align__(16) float As[32 * LDA];   // 16.9 KB
    __shared__ __align__(16) float Ws[16 * WCG];   // 16.6 KB
    const int tid = threadIdx.x;
    const int r0 = blockIdx.x * 128;
    const int c0 = blockIdx.y * 128;
    const int ty = tid >> 4, tx = tid & 15;

#define PACC(i) f4v accL##i = {0.f,0.f,0.f,0.f}; f4v accR##i = {0.f,0.f,0.f,0.f};
    REP8(PACC)
#undef PACC

    for (int kk = 0; kk < K; kk += 32) {
        __syncthreads();
        // stage A chunk transposed: As[k][row]
#pragma unroll
        for (int i = 0; i < 4; ++i) {
            int idx = tid + i * 256;          // 1024 float4 slots: 128 rows x 8 kgroups
            int row = idx >> 3, kg = idx & 7;
            int k = kk + kg * 4;
            f4v v = {0.f, 0.f, 0.f, 0.f};
            if (k < K) v = *(const f4v*)&A[(size_t)(r0 + row) * K + k];
            As[(kg * 4 + 0) * LDA + row] = v.x;
            As[(kg * 4 + 1) * LDA + row] = v.y;
            As[(kg * 4 + 2) * LDA + row] = v.z;
            As[(kg * 4 + 3) * LDA + row] = v.w;
        }
        // stage W chunk: Ws[cg][k*8 + half*4]
#pragma unroll
        for (int i = 0; i < 4; ++i) {
            int idx = tid + i * 256;          // 1024 float4 slots: 32 k x 32 colquads
            int k = idx >> 5, q = idx & 31;
            int gk = kk + k, gc = c0 + q * 4;
            f4v v = {0.f, 0.f, 0.f, 0.f};
            if (gk < K && gc < N) v = *(const f4v*)&W[(size_t)gk * N + gc];
            int cg = q >> 1, half = q & 1;
            *(f4v*)&Ws[cg * WCG + k * 8 + half * 4] = v;
        }
        __syncthreads();
#pragma unroll
        for (int k = 0; k < 32; ++k) {
            f4v av0 = *(const f4v*)&As[k * LDA + ty * 8];
            f4v av1 = *(const f4v*)&As[k * LDA + ty * 8 + 4];
            f4v b0v = *(const f4v*)&Ws[tx * WCG + k * 8];
            f4v b1v = *(const f4v*)&Ws[tx * WCG + k * 8 + 4];
#define PFMA(i, s) accL##i += (s) * b0v; accR##i += (s) * b1v;
            PFMA(0, av0.x) PFMA(1, av0.y) PFMA(2, av0.z) PFMA(3, av0.w)
            PFMA(4, av1.x) PFMA(5, av1.y) PFMA(6, av1.z) PFMA(7, av1.w)
#undef PFMA
        }
    }

    // epilogue: + bias, guarded f4 stores
    const int cb = c0 + tx * 8;
    float b0 = (cb + 0 < N) ? bias[cb + 0] : 0.f;
    float b1 = (cb + 1 < N) ? bias[cb + 1] : 0.f;
    float b2 = (cb + 2 < N) ? bias[cb + 2] : 0.f;
    float b3 = (cb + 3 < N) ? bias[cb + 3] : 0.f;
    float b4 = (cb + 4 < N) ? bias[cb + 4] : 0.f;
    float b5 = (cb + 5 < N) ? bias[cb + 5] : 0.f;
    float b6 = (cb + 6 < N) ? bias[cb + 6] : 0.f;
    float b7 = (cb + 7 < N) ? bias[cb + 7] : 0.f;
    f4v bL = {b0, b1, b2, b3};
    f4v bR = {b4, b5, b6, b7};
#define PST(i) { \
        int r = r0 + ty * 8 + i; \
        size_t orow = SWAP ? ((size_t)(r & 255) * BATCH + (r >> 8)) : (size_t)r; \
        if (cb < N)     { f4v v = accL##i + bL; *(f4v*)&out[orow * N + cb] = v; } \
        if (cb + 4 < N) { f4v v = accR##i + bR; *(f4v*)&out[orow * N + cb + 4] = v; } }
    REP8(PST)
#undef PST
}

// unconditional clamped-row weight column load (branchless).
// Rows >= H1 read row H1-1 (garbage value) -- nullified because hsP pad = 0.
__device__ __forceinline__ f4v ldw_(const float* __restrict__ U1, int kb, int col) {
    int k0 = (kb + 0 < H1) ? kb + 0 : H1 - 1;
    int k1 = (kb + 1 < H1) ? kb + 1 : H1 - 1;
    int k2 = (kb + 2 < H1) ? kb + 2 : H1 - 1;
    int k3 = (kb + 3 < H1) ? kb + 3 : H1 - 1;
    f4v v;
    v.x = U1[(size_t)k0 * 400 + col];
    v.y = U1[(size_t)k1 * 400 + col];
    v.z = U1[(size_t)k2 * 400 + col];
    v.w = U1[(size_t)k3 * 400 + col];
    return v;
}

// =================== recurrence, layer 1 (r10: best measured, 460us) ===================
// 512 threads, lane map tid = cl*4 + kq: cl = tid>>2 (0..127, active < 100),
// kq = tid&3 (k-quarter over padded K=112, 28 k each = 7 f4v). Thread owns the
// GATE QUAD cols {cl, 100+cl, 200+cl, 300+cl}; k-reduce = 2x shfl_xor in-wave.
// Weights: 28 f4v, one-time load + one-time asm pin. Known behavior: allocator
// splits part of the set to AGPRs (VGPR_Count=88) -- accepted; this is the
// fastest measured variant of rec1 across 11 designs.
__global__ __launch_bounds__(512)
__attribute__((amdgpu_waves_per_eu(2, 2)))
void rec1_kernel(const float* __restrict__ zx,   // [T][B][400]
                 const float* __restrict__ U1,   // [100][400]
                 float* __restrict__ h1seq)      // [T][B][100]
{
    const int row = blockIdx.x;
    const int tid = threadIdx.x;
    const int cl = tid >> 2;      // column 0..127 (active < 100)
    const int kq = tid & 3;       // k-quarter
    const int cc = (cl < H1) ? cl : 0;   // clamp; clamped lanes never store
    __shared__ __align__(16) float hsP[2][112];  // double-buffered h state (pad 100..111 = 0)

    // one-time weight load: 28 f4v SSA values (4 gate-cols x 7 f4v of k)
#define R1W(j) \
    f4v w0_##j = ldw_(U1, kq * 28 + 4 * (j), cc); \
    f4v w1_##j = ldw_(U1, kq * 28 + 4 * (j), 100 + cc); \
    f4v w2_##j = ldw_(U1, kq * 28 + 4 * (j), 200 + cc); \
    f4v w3_##j = ldw_(U1, kq * 28 + 4 * (j), 300 + cc);
    REP7(R1W)
#undef R1W
    // one-time pin (r10): asm outputs cannot be rematerialized
#define R1P(j) asm volatile("" : "+v"(w0_##j), "+v"(w1_##j), "+v"(w2_##j), "+v"(w3_##j));
    REP7(R1P)
#undef R1P

    if (tid < 112) { hsP[0][tid] = 0.0f; hsP[1][tid] = 0.0f; }
    const bool tail = (kq == 0) && (cl < H1);
    float cst = 0.0f;
    float zc0 = 0.f, zc1 = 0.f, zc2 = 0.f, zc3 = 0.f;
    if (tail) {
        const float* pz = zx + (size_t)row * 400 + cl;
        zc0 = pz[0]; zc1 = pz[100]; zc2 = pz[200]; zc3 = pz[300];
    }
    __syncthreads();

    for (int t = 0; t < T_SEQ; ++t) {
        // prefetch next step's zx FIRST -- latency hides under the FMA phase
        float zn0 = 0.f, zn1 = 0.f, zn2 = 0.f, zn3 = 0.f;
        if (tail) {
            int tn = (t + 1 < T_SEQ) ? t + 1 : t;
            const float* pz = zx + ((size_t)tn * BATCH + row) * 400 + cl;
            zn0 = pz[0]; zn1 = pz[100]; zn2 = pz[200]; zn3 = pz[300];
        }

        const float* hb = hsP[t & 1];
        f4v s0 = {0.f, 0.f, 0.f, 0.f};
        f4v s1 = {0.f, 0.f, 0.f, 0.f};
        f4v s2 = {0.f, 0.f, 0.f, 0.f};
        f4v s3 = {0.f, 0.f, 0.f, 0.f};
#define R1F(j) { f4v hv = *(const f4v*)&hb[kq * 28 + 4 * (j)]; \
        s0 += hv * w0_##j; s1 += hv * w1_##j; s2 += hv * w2_##j; s3 += hv * w3_##j; }
        REP7(R1F)
#undef R1F
        float a0 = hsum4_(s0);
        float a1 = hsum4_(s1);
        float a2 = hsum4_(s2);
        float a3 = hsum4_(s3);
        // k-reduce across the 4 kq lanes (adjacent lanes, same wave)
        a0 += __shfl_xor(a0, 1, 64); a0 += __shfl_xor(a0, 2, 64);
        a1 += __shfl_xor(a1, 1, 64); a1 += __shfl_xor(a1, 2, 64);
        a2 += __shfl_xor(a2, 1, 64); a2 += __shfl_xor(a2, 2, 64);
        a3 += __shfl_xor(a3, 1, 64); a3 += __shfl_xor(a3, 2, 64);

        if (tail) {
            float z0 = zc0 + a0;                 // gate order i, f, g, o
            float z1 = zc1 + a1;
            float z2 = zc2 + a2;
            float z3 = zc3 + a3;
            float iv = sigmoidf_(z0);
            float fv = sigmoidf_(z1);
            float gv = fmaxf(z2, 0.0f);          // g: relu
            float ov = sigmoidf_(z3);
            cst = fv * cst + iv * gv;            // c = f*c + i*g
            float h = ov * fmaxf(cst, 0.0f);     // h = o*relu(c)
            hsP[(t + 1) & 1][cl] = h;            // write NEXT buffer: no WAR race
            h1seq[((size_t)t * BATCH + row) * H1 + cl] = h;
            zc0 = zn0; zc1 = zn1; zc2 = zn2; zc3 = zn3;
        }
        __syncthreads();
    }
}

// =================== recurrence, layer 2 (time-chunked, 2 barriers/step) ===================
// 4-way k-split: thread (kq=tid>>7, cl=tid&127) covers k in [kq*32,kq*32+32)
// for cols {cl, cl+128, cl+256, cl+384}. 32 f4v SSA weights + pin.
// r16 change: za stage removed. tid<128 reads its 16 zp partials + OWN 4 zx
// columns, computes all gates in-thread, updates c, writes hs. hs write after
// barrier#1 is safe: all FMA hs-reads precede the zp writes before barrier#1.
template<bool INIT, bool LAST>
__global__ __launch_bounds__(512)
__attribute__((amdgpu_waves_per_eu(2, 2)))
void rec2_chunk(const float* __restrict__ zx,    // [tlen][B][512] (bias included)
                const float* __restrict__ U2,    // [128][512]
                float* __restrict__ cbuf,        // [B][128]
                float* __restrict__ hbuf,        // [B][128]
                float* __restrict__ h2out,       // [B][128] (used when LAST)
                int tlen)
{
    const int row = blockIdx.x;
    const int tid = threadIdx.x;   // 0..511
    const int kq = tid >> 7;
    const int cl = tid & 127;
    __shared__ __align__(16) float hs[H2];
    __shared__ float zp[4 * 512];

#define R2_LD(j) \
    f4v w0_##j, w1_##j, w2_##j, w3_##j; { \
        const float* p = U2 + (size_t)(kq * 32 + 4 * j) * 512 + cl; \
        w0_##j = (f4v){p[0],   p[512],       p[1024],       p[1536]}; \
        w1_##j = (f4v){p[128], p[512 + 128], p[1024 + 128], p[1536 + 128]}; \
        w2_##j = (f4v){p[256], p[512 + 256], p[1024 + 256], p[1536 + 256]}; \
        w3_##j = (f4v){p[384], p[512 + 384], p[1024 + 384], p[1536 + 384]}; }
    REP8(R2_LD)
#undef R2_LD
    // pin weights (r10: harmless here, keeps the gather rooted)
#define R2P(j) asm volatile("" : "+v"(w0_##j), "+v"(w1_##j), "+v"(w2_##j), "+v"(w3_##j));
    REP8(R2P)
#undef R2P

    const bool upd = (tid < H2);
    float cst = 0.0f;
    if (upd) {
        if (INIT) {
            hs[tid] = 0.0f;
        } else {
            hs[tid] = hbuf[(size_t)row * H2 + tid];
            cst = cbuf[(size_t)row * H2 + tid];
        }
    }
    // updater threads own all 4 gate columns {tid, tid+128, tid+256, tid+384}
    float zc0 = 0.f, zc1 = 0.f, zc2 = 0.f, zc3 = 0.f;
    if (upd) {
        const float* pz = zx + (size_t)row * 512 + tid;
        zc0 = pz[0]; zc1 = pz[128]; zc2 = pz[256]; zc3 = pz[384];
    }
    __syncthreads();

    for (int t = 0; t < tlen; ++t) {
        // prefetch next step's zx (updater threads only)
        float zn0 = 0.f, zn1 = 0.f, zn2 = 0.f, zn3 = 0.f;
        if (upd) {
            int tn = (t + 1 < tlen) ? t + 1 : t;
            const float* pz = zx + ((size_t)tn * BATCH + row) * 512 + tid;
            zn0 = pz[0]; zn1 = pz[128]; zn2 = pz[256]; zn3 = pz[384];
        }

        f4v s0 = {0.f, 0.f, 0.f, 0.f};
        f4v s1 = {0.f, 0.f, 0.f, 0.f};
        f4v s2 = {0.f, 0.f, 0.f, 0.f};
        f4v s3 = {0.f, 0.f, 0.f, 0.f};
#define R2_FMA(j) { f4v hv = *(const f4v*)&hs[kq * 32 + 4 * j]; \
        s0 += hv * w0_##j; s1 += hv * w1_##j; s2 += hv * w2_##j; s3 += hv * w3_##j; }
        REP8(R2_FMA)
#undef R2_FMA
        zp[kq * 512 + cl]       = hsum4_(s0);
        zp[kq * 512 + cl + 128] = hsum4_(s1);
        zp[kq * 512 + cl + 256] = hsum4_(s2);
        zp[kq * 512 + cl + 384] = hsum4_(s3);
        __syncthreads();   // barrier 1: zp complete; hs FMA-reads also complete

        if (upd) {
            float z0 = zc0 + (zp[tid]        + zp[512 + tid])
                           + (zp[1024 + tid] + zp[1536 + tid]);
            float z1 = zc1 + (zp[tid + 128]  + zp[512 + tid + 128])
                           + (zp[1024 + tid + 128] + zp[1536 + tid + 128]);
            float z2 = zc2 + (zp[tid + 256]  + zp[512 + tid + 256])
                           + (zp[1024 + tid + 256] + zp[1536 + tid + 256]);
            float z3 = zc3 + (zp[tid + 384]  + zp[512 + tid + 384])
                           + (zp[1024 + tid + 384] + zp[1536 + tid + 384]);
            float iv = sigmoidf_(z0);            // gate order i, f, g, o
            float fv = sigmoidf_(z1);
            float gv = fmaxf(z2, 0.0f);          // candidate: relu
            float ov = sigmoidf_(z3);
            cst = fv * cst + iv * gv;            // c = f*c + i*g
            hs[tid] = ov * fmaxf(cst, 0.0f);     // h = o*relu(c)
            zc0 = zn0; zc1 = zn1; zc2 = zn2; zc3 = zn3;
        }
        __syncthreads();   // barrier 2: hs(t+1) visible to all
    }

    if (upd) {
        float h = hs[tid];
        cbuf[(size_t)row * H2 + tid] = cst;
        hbuf[(size_t)row * H2 + tid] = h;
        if (LAST) h2out[(size_t)row * H2 + tid] = h;
    }
}

// =================== dense + softmax ===================
__global__ __launch_bounds__(64, 1)
void dense_softmax_kernel(const float* __restrict__ h2, const float* __restrict__ Wd,
                          const float* __restrict__ bd, float* __restrict__ out)
{
    const int b = blockIdx.x;
    const int k = threadIdx.x;
    __shared__ __align__(16) float hsm[H2];
    if (k < H2 / 4) ((f4v*)hsm)[k] = ((const f4v*)(h2 + (size_t)b * H2))[k];
    __syncthreads();

    float logit = -1e30f;
    if (k < NCLS) {
        float acc = bd[k];
#pragma unroll
        for (int d = 0; d < H2; ++d) acc += hsm[d] * Wd[d * NCLS + k];
        logit = acc;
    }
    float m = logit;
#pragma unroll
    for (int off = 32; off >= 1; off >>= 1) m = fmaxf(m, __shfl_xor(m, off, 64));
    float e = (k < NCLS) ? __expf(logit - m) : 0.0f;
    float s = e;
#pragma unroll
    for (int off = 32; off >= 1; off >>= 1) s += __shfl_xor(s, off, 64);
    if (k < NCLS) out[(size_t)b * NCLS + k] = e / s;
}

// =================== fallback (round-1) kernels ===================
__global__ __launch_bounds__(448, 1)
void lstm1_fb(const float* __restrict__ x, const float* __restrict__ W1,
              const float* __restrict__ U1, const float* __restrict__ b1,
              float* __restrict__ h1out)
{
    const int b = blockIdx.x;
    const int k = threadIdx.x;
    __shared__ __align__(16) float xs[IN_DIM];
    __shared__ __align__(16) float hs[H1];
    __shared__ __align__(16) float zs[4 * H1];
    float w1r[IN_DIM];
    float u1r[H1];
    float bias = 0.0f;
    if (k < 4 * H1) {
        bias = b1[k];
#pragma unroll
        for (int d = 0; d < IN_DIM; ++d) w1r[d] = W1[d * (4 * H1) + k];
#pragma unroll
        for (int j = 0; j < H1; ++j) u1r[j] = U1[j * (4 * H1) + k];
    }
    if (k < H1) hs[k] = 0.0f;
    if (k < IN_DIM / 4)
        ((float4*)xs)[k] = ((const float4*)(x + ((size_t)b * T_SEQ) * IN_DIM))[k];
    float c = 0.0f;
    __syncthreads();
    for (int t = 0; t < T_SEQ; ++t) {
        if (k < 4 * H1) {
            float acc0 = bias, acc1 = 0.f, acc2 = 0.f, acc3 = 0.f;
#pragma unroll
            for (int q = 0; q < IN_DIM / 4; ++q) {
                float4 xv = ((const float4*)xs)[q];
                acc0 += xv.x * w1r[4 * q]; acc1 += xv.y * w1r[4 * q + 1];
                acc2 += xv.z * w1r[4 * q + 2]; acc3 += xv.w * w1r[4 * q + 3];
            }
#pragma unroll
            for (int q = 0; q < H1 / 4; ++q) {
                float4 hv = ((const float4*)hs)[q];
                acc0 += hv.x * u1r[4 * q]; acc1 += hv.y * u1r[4 * q + 1];
                acc2 += hv.z * u1r[4 * q + 2]; acc3 += hv.w * u1r[4 * q + 3];
            }
            float zv = (acc0 + acc1) + (acc2 + acc3);
            zs[k] = (k >= 2 * H1 && k < 3 * H1) ? fmaxf(zv, 0.0f) : sigmoidf_(zv);
        }
        __syncthreads();
        if (k < H1) {
            float i = zs[k], f = zs[k + H1], g = zs[k + 2 * H1], o = zs[k + 3 * H1];
            c = f * c + i * g;
            float h = o * fmaxf(c, 0.0f);
            hs[k] = h;
            h1out[((size_t)t * BATCH + b) * H1 + k] = h;
        }
        int tn = t + 1;
        if (tn < T_SEQ && k < IN_DIM / 4)
            ((float4*)xs)[k] = ((const float4*)(x + ((size_t)b * T_SEQ + tn) * IN_DIM))[k];
        __syncthreads();
    }
}

__global__ __launch_bounds__(512, 1)
void lstm2_fb(const float* __restrict__ h1in, const float* __restrict__ W2,
              const float* __restrict__ U2, const float* __restrict__ b2,
              float* __restrict__ h2out)
{
    const int b = blockIdx.x;
    const int k = threadIdx.x;
    __shared__ __align__(16) float ps[H1];
    __shared__ __align__(16) float hs[H2];
    __shared__ __align__(16) float zs[4 * H2];
    float w2r[H1];
    float u2r[H2];
    float bias = b2[k];
#pragma unroll
    for (int j = 0; j < H1; ++j) w2r[j] = W2[j * (4 * H2) + k];
#pragma unroll
    for (int j = 0; j < H2; ++j) u2r[j] = U2[j * (4 * H2) + k];
    if (k < H2) hs[k] = 0.0f;
    if (k < H1 / 4)
        ((float4*)ps)[k] = ((const float4*)(h1in + (size_t)b * H1))[k];
    float c = 0.0f;
    float hlast = 0.0f;
    __syncthreads();
    for (int t = 0; t < T_SEQ; ++t) {
        float acc0 = bias, acc1 = 0.f, acc2 = 0.f, acc3 = 0.f;
#pragma unroll
        for (int q = 0; q < H1 / 4; ++q) {
            float4 pv = ((const float4*)ps)[q];
            acc0 += pv.x * w2r[4 * q]; acc1 += pv.y * w2r[4 * q + 1];
            acc2 += pv.z * w2r[4 * q + 2]; acc3 += pv.w * w2r[4 * q + 3];
        }
#pragma unroll
        for (int q = 0; q < H2 / 4; ++q) {
            float4 hv = ((const float4*)hs)[q];
            acc0 += hv.x * u2r[4 * q]; acc1 += hv.y * u2r[4 * q + 1];
            acc2 += hv.z * u2r[4 * q + 2]; acc3 += hv.w * u2r[4 * q + 3];
        }
        float zv = (acc0 + acc1) + (acc2 + acc3);
        zs[k] = (k >= 2 * H2 && k < 3 * H2) ? fmaxf(zv, 0.0f) : sigmoidf_(zv);
        __syncthreads();
        if (k < H2) {
            float i = zs[k], f = zs[k + H2], g = zs[k + 2 * H2], o = zs[k + 3 * H2];
            c = f * c + i * g;
            hlast = o * fmaxf(c, 0.0f);
            hs[k] = hlast;
        }
        int tn = t + 1;
        if (tn < T_SEQ && k < H1 / 4)
            ((float4*)ps)[k] = ((const float4*)(h1in + ((size_t)tn * BATCH + b) * H1))[k];
        __syncthreads();
    }
    if (k < H2) h2out[(size_t)b * H2 + k] = hlast;
}

extern "C" void kernel_launch(void* const* d_in, const int* in_sizes, int n_in,
                              void* d_out, int out_size, void* d_ws, size_t ws_size,
                              hipStream_t stream) {
    const float* x  = (const float*)d_in[0];
    const float* W1 = (const float*)d_in[1];
    const float* U1 = (const float*)d_in[2];
    const float* b1 = (const float*)d_in[3];
    const float* W2 = (const float*)d_in[4];
    const float* U2 = (const float*)d_in[5];
    const float* b2 = (const float*)d_in[6];
    const float* Wd = (const float*)d_in[7];
    const float* bd = (const float*)d_in[8];
    float* out = (float*)d_out;

    const size_t zx_elems = (size_t)T_SEQ * BATCH * 400;   // 52428800
    const size_t h1_elems = (size_t)T_SEQ * BATCH * H1;    // 13107200
    const size_t st_elems = (size_t)BATCH * H2;            // 65536
    const size_t need = (zx_elems + h1_elems + 3 * st_elems) * sizeof(float);  // 262.93 MB

    if (ws_size >= need) {
        float* zxbuf = (float*)d_ws;
        float* h1buf = zxbuf + zx_elems;
        float* cbuf  = h1buf + h1_elems;
        float* hbuf  = cbuf + st_elems;
        float* h2buf = hbuf + st_elems;
        const int TC = T_SEQ / 2;   // 128-step chunks

        // zx1 = x @ W1 + b1 -> [T][B][400]
        hipLaunchKernelGGL((proj_kernel<IN_DIM, 4 * H1, true>), dim3(1024, 4), dim3(256), 0, stream,
                           x, W1, b1, zxbuf);
        hipLaunchKernelGGL(rec1_kernel, dim3(BATCH), dim3(512), 0, stream,
                           zxbuf, U1, h1buf);
        // ---- layer 2, chunk A (t = 0..127): zx2 chunk overwrites zx1 region ----
        hipLaunchKernelGGL((proj_kernel<H1, 4 * H2, false>), dim3(512, 4), dim3(256), 0, stream,
                           h1buf, W2, b2, zxbuf);
        hipLaunchKernelGGL((rec2_chunk<true, false>), dim3(BATCH), dim3(512), 0, stream,
                           zxbuf, U2, cbuf, hbuf, h2buf, TC);
        // ---- layer 2, chunk B (t = 128..255) ----
        hipLaunchKernelGGL((proj_kernel<H1, 4 * H2, false>), dim3(512, 4), dim3(256), 0, stream,
                           h1buf + (size_t)TC * BATCH * H1, W2, b2, zxbuf);
        hipLaunchKernelGGL((rec2_chunk<false, true>), dim3(BATCH), dim3(512), 0, stream,
                           zxbuf, U2, cbuf, hbuf, h2buf, TC);

        hipLaunchKernelGGL(dense_softmax_kernel, dim3(BATCH), dim3(64), 0, stream,
                           h2buf, Wd, bd, out);
    } else {
        // fallback: round-1 fused kernels (needs ~52.7 MB)
        float* h1buf = (float*)d_ws;
        float* h2buf = h1buf + h1_elems;
        hipLaunchKernelGGL(lstm1_fb, dim3(BATCH), dim3(448), 0, stream, x, W1, U1, b1, h1buf);
        hipLaunchKernelGGL(lstm2_fb, dim3(BATCH), dim3(512), 0, stream, h1buf, W2, U2, b2, h2buf);
        hipLaunchKernelGGL(dense_softmax_kernel, dim3(BATCH), dim3(64), 0, stream, h2buf, Wd, bd, out);
    }
}

// Round 12
// 1271.185 us; speedup vs baseline: 1.2854x; 1.0299x over previous
//
#include <hip/hip_runtime.h>
#include <math.h>

// TfLSTM: x[512,256,128] -> LSTM(100, relu) -> LSTM(128, relu, last) -> Dense(19) -> softmax
// Round 17: ONE change -- proj __launch_bounds__(256,2) -> (256,4).
//   r16 accounting: total 1309 = rec1 455 + ~854 (proj1 + 2xproj2 + 2xrec2 +
//   dense, never individually profiled). proj VGPR=128 exactly and LDS
//   33.5KB -> 4 blocks/CU fit BOTH budgets; (256,2) only guaranteed 2. At 4
//   blocks/CU, one block's staging barriers overlap another's FMA phase.
//   This is also the discriminating experiment: total moves -> proj was the
//   consumer; flat -> rec2 is, and next round targets rec2.
// CLOSED BRANCHES (do not revisit):
//  - rec1 register path: allocator holds ~budget/2 loop-invariants at every
//    waves_per_eu tried (r5-r12); per-step ~2130cy; r10 structure = best (455us).
//  - rec1 LDS-weights (r15): bank aliasing + 520 ds_read/step floor ~560us.
//  - proj dbuf w/ lambda reg arrays (r13): scratch spill (6.8GB writes).
//  - rec2 3->2 barriers (r16): neutral -- rec2 not barrier-bound.
//   ws layout (floats): zxbuf 209.7MB | h1seq 52.4MB | cbuf/hbuf/h2buf 0.26MB ea.

#define T_SEQ 256
#define BATCH 512
#define IN_DIM 128
#define H1 100
#define H2 128
#define NCLS 19

typedef float f4v __attribute__((ext_vector_type(4)));

__device__ __forceinline__ float sigmoidf_(float x) {
    return 1.0f / (1.0f + __expf(-x));
}
__device__ __forceinline__ float hsum4_(f4v v) {
    return (v.x + v.y) + (v.z + v.w);
}

#define REP4(M)  M(0) M(1) M(2) M(3)
#define REP7(M)  M(0) M(1) M(2) M(3) M(4) M(5) M(6)
#define REP8(M)  M(0) M(1) M(2) M(3) M(4) M(5) M(6) M(7)

// =================== projection GEMM (r14 structure, 4 blocks/CU) ===================
template<int K, int N, bool SWAP>
__global__ __launch_bounds__(256, 4)
void proj_kernel(const float* __restrict__ A, const float* __restrict__ W,
                 const float* __restrict__ bias, float* __restrict__ out)
{
    constexpr int LDA = 132;  // As row stride
    constexpr int WCG = 260;  // Ws colgroup stride (32*8 + 4)
    __shared__ __align__(16) float As[32 * LDA];   // 16.9 KB
    __shared__ __align__(16) float Ws[16 * WCG];   // 16.6 KB
    const int tid = threadIdx.x;
    const int r0 = blockIdx.x * 128;
    const int c0 = blockIdx.y * 128;
    const int ty = tid >> 4, tx = tid & 15;

#define PACC(i) f4v accL##i = {0.f,0.f,0.f,0.f}; f4v accR##i = {0.f,0.f,0.f,0.f};
    REP8(PACC)
#undef PACC

    for (int kk = 0; kk < K; kk += 32) {
        __syncthreads();
        // stage A chunk transposed: As[k][row]
#pragma unroll
        for (int i = 0; i < 4; ++i) {
            int idx = tid + i * 256;          // 1024 float4 slots: 128 rows x 8 kgroups
            int row = idx >> 3, kg = idx & 7;
            int k = kk + kg * 4;
            f4v v = {0.f, 0.f, 0.f, 0.f};
            if (k < K) v = *(const f4v*)&A[(size_t)(r0 + row) * K + k];
            As[(kg * 4 + 0) * LDA + row] = v.x;
            As[(kg * 4 + 1) * LDA + row] = v.y;
            As[(kg * 4 + 2) * LDA + row] = v.z;
            As[(kg * 4 + 3) * LDA + row] = v.w;
        }
        // stage W chunk: Ws[cg][k*8 + half*4]
#pragma unroll
        for (int i = 0; i < 4; ++i) {
            int idx = tid + i * 256;          // 1024 float4 slots: 32 k x 32 colquads
            int k = idx >> 5, q = idx & 31;
            int gk = kk + k, gc = c0 + q * 4;
            f4v v = {0.f, 0.f, 0.f, 0.f};
            if (gk < K && gc < N) v = *(const f4v*)&W[(size_t)gk * N + gc];
            int cg = q >> 1, half = q & 1;
            *(f4v*)&Ws[cg * WCG + k * 8 + half * 4] = v;
        }
        __syncthreads();
#pragma unroll
        for (int k = 0; k < 32; ++k) {
            f4v av0 = *(const f4v*)&As[k * LDA + ty * 8];
            f4v av1 = *(const f4v*)&As[k * LDA + ty * 8 + 4];
            f4v b0v = *(const f4v*)&Ws[tx * WCG + k * 8];
            f4v b1v = *(const f4v*)&Ws[tx * WCG + k * 8 + 4];
#define PFMA(i, s) accL##i += (s) * b0v; accR##i += (s) * b1v;
            PFMA(0, av0.x) PFMA(1, av0.y) PFMA(2, av0.z) PFMA(3, av0.w)
            PFMA(4, av1.x) PFMA(5, av1.y) PFMA(6, av1.z) PFMA(7, av1.w)
#undef PFMA
        }
    }

    // epilogue: + bias, guarded f4 stores
    const int cb = c0 + tx * 8;
    float b0 = (cb + 0 < N) ? bias[cb + 0] : 0.f;
    float b1 = (cb + 1 < N) ? bias[cb + 1] : 0.f;
    float b2 = (cb + 2 < N) ? bias[cb + 2] : 0.f;
    float b3 = (cb + 3 < N) ? bias[cb + 3] : 0.f;
    float b4 = (cb + 4 < N) ? bias[cb + 4] : 0.f;
    float b5 = (cb + 5 < N) ? bias[cb + 5] : 0.f;
    float b6 = (cb + 6 < N) ? bias[cb + 6] : 0.f;
    float b7 = (cb + 7 < N) ? bias[cb + 7] : 0.f;
    f4v bL = {b0, b1, b2, b3};
    f4v bR = {b4, b5, b6, b7};
#define PST(i) { \
        int r = r0 + ty * 8 + i; \
        size_t orow = SWAP ? ((size_t)(r & 255) * BATCH + (r >> 8)) : (size_t)r; \
        if (cb < N)     { f4v v = accL##i + bL; *(f4v*)&out[orow * N + cb] = v; } \
        if (cb + 4 < N) { f4v v = accR##i + bR; *(f4v*)&out[orow * N + cb + 4] = v; } }
    REP8(PST)
#undef PST
}

// unconditional clamped-row weight column load (branchless).
// Rows >= H1 read row H1-1 (garbage value) -- nullified because hsP pad = 0.
__device__ __forceinline__ f4v ldw_(const float* __restrict__ U1, int kb, int col) {
    int k0 = (kb + 0 < H1) ? kb + 0 : H1 - 1;
    int k1 = (kb + 1 < H1) ? kb + 1 : H1 - 1;
    int k2 = (kb + 2 < H1) ? kb + 2 : H1 - 1;
    int k3 = (kb + 3 < H1) ? kb + 3 : H1 - 1;
    f4v v;
    v.x = U1[(size_t)k0 * 400 + col];
    v.y = U1[(size_t)k1 * 400 + col];
    v.z = U1[(size_t)k2 * 400 + col];
    v.w = U1[(size_t)k3 * 400 + col];
    return v;
}

// =================== recurrence, layer 1 (r10: best measured, 455us) ===================
// 512 threads, lane map tid = cl*4 + kq: cl = tid>>2 (0..127, active < 100),
// kq = tid&3 (k-quarter over padded K=112, 28 k each = 7 f4v). Thread owns the
// GATE QUAD cols {cl, 100+cl, 200+cl, 300+cl}; k-reduce = 2x shfl_xor in-wave.
// Weights: 28 f4v, one-time load + one-time asm pin. Known behavior: allocator
// splits part of the set to AGPRs (VGPR_Count=88) -- accepted; fastest of 11
// rec1 designs measured.
__global__ __launch_bounds__(512)
__attribute__((amdgpu_waves_per_eu(2, 2)))
void rec1_kernel(const float* __restrict__ zx,   // [T][B][400]
                 const float* __restrict__ U1,   // [100][400]
                 float* __restrict__ h1seq)      // [T][B][100]
{
    const int row = blockIdx.x;
    const int tid = threadIdx.x;
    const int cl = tid >> 2;      // column 0..127 (active < 100)
    const int kq = tid & 3;       // k-quarter
    const int cc = (cl < H1) ? cl : 0;   // clamp; clamped lanes never store
    __shared__ __align__(16) float hsP[2][112];  // double-buffered h state (pad 100..111 = 0)

    // one-time weight load: 28 f4v SSA values (4 gate-cols x 7 f4v of k)
#define R1W(j) \
    f4v w0_##j = ldw_(U1, kq * 28 + 4 * (j), cc); \
    f4v w1_##j = ldw_(U1, kq * 28 + 4 * (j), 100 + cc); \
    f4v w2_##j = ldw_(U1, kq * 28 + 4 * (j), 200 + cc); \
    f4v w3_##j = ldw_(U1, kq * 28 + 4 * (j), 300 + cc);
    REP7(R1W)
#undef R1W
    // one-time pin (r10): asm outputs cannot be rematerialized
#define R1P(j) asm volatile("" : "+v"(w0_##j), "+v"(w1_##j), "+v"(w2_##j), "+v"(w3_##j));
    REP7(R1P)
#undef R1P

    if (tid < 112) { hsP[0][tid] = 0.0f; hsP[1][tid] = 0.0f; }
    const bool tail = (kq == 0) && (cl < H1);
    float cst = 0.0f;
    float zc0 = 0.f, zc1 = 0.f, zc2 = 0.f, zc3 = 0.f;
    if (tail) {
        const float* pz = zx + (size_t)row * 400 + cl;
        zc0 = pz[0]; zc1 = pz[100]; zc2 = pz[200]; zc3 = pz[300];
    }
    __syncthreads();

    for (int t = 0; t < T_SEQ; ++t) {
        // prefetch next step's zx FIRST -- latency hides under the FMA phase
        float zn0 = 0.f, zn1 = 0.f, zn2 = 0.f, zn3 = 0.f;
        if (tail) {
            int tn = (t + 1 < T_SEQ) ? t + 1 : t;
            const float* pz = zx + ((size_t)tn * BATCH + row) * 400 + cl;
            zn0 = pz[0]; zn1 = pz[100]; zn2 = pz[200]; zn3 = pz[300];
        }

        const float* hb = hsP[t & 1];
        f4v s0 = {0.f, 0.f, 0.f, 0.f};
        f4v s1 = {0.f, 0.f, 0.f, 0.f};
        f4v s2 = {0.f, 0.f, 0.f, 0.f};
        f4v s3 = {0.f, 0.f, 0.f, 0.f};
#define R1F(j) { f4v hv = *(const f4v*)&hb[kq * 28 + 4 * (j)]; \
        s0 += hv * w0_##j; s1 += hv * w1_##j; s2 += hv * w2_##j; s3 += hv * w3_##j; }
        REP7(R1F)
#undef R1F
        float a0 = hsum4_(s0);
        float a1 = hsum4_(s1);
        float a2 = hsum4_(s2);
        float a3 = hsum4_(s3);
        // k-reduce across the 4 kq lanes (adjacent lanes, same wave)
        a0 += __shfl_xor(a0, 1, 64); a0 += __shfl_xor(a0, 2, 64);
        a1 += __shfl_xor(a1, 1, 64); a1 += __shfl_xor(a1, 2, 64);
        a2 += __shfl_xor(a2, 1, 64); a2 += __shfl_xor(a2, 2, 64);
        a3 += __shfl_xor(a3, 1, 64); a3 += __shfl_xor(a3, 2, 64);

        if (tail) {
            float z0 = zc0 + a0;                 // gate order i, f, g, o
            float z1 = zc1 + a1;
            float z2 = zc2 + a2;
            float z3 = zc3 + a3;
            float iv = sigmoidf_(z0);
            float fv = sigmoidf_(z1);
            float gv = fmaxf(z2, 0.0f);          // g: relu
            float ov = sigmoidf_(z3);
            cst = fv * cst + iv * gv;            // c = f*c + i*g
            float h = ov * fmaxf(cst, 0.0f);     // h = o*relu(c)
            hsP[(t + 1) & 1][cl] = h;            // write NEXT buffer: no WAR race
            h1seq[((size_t)t * BATCH + row) * H1 + cl] = h;
            zc0 = zn0; zc1 = zn1; zc2 = zn2; zc3 = zn3;
        }
        __syncthreads();
    }
}

// =================== recurrence, layer 2 (time-chunked, 2 barriers/step) ===================
template<bool INIT, bool LAST>
__global__ __launch_bounds__(512)
__attribute__((amdgpu_waves_per_eu(2, 2)))
void rec2_chunk(const float* __restrict__ zx,    // [tlen][B][512] (bias included)
                const float* __restrict__ U2,    // [128][512]
                float* __restrict__ cbuf,        // [B][128]
                float* __restrict__ hbuf,        // [B][128]
                float* __restrict__ h2out,       // [B][128] (used when LAST)
                int tlen)
{
    const int row = blockIdx.x;
    const int tid = threadIdx.x;   // 0..511
    const int kq = tid >> 7;
    const int cl = tid & 127;
    __shared__ __align__(16) float hs[H2];
    __shared__ float zp[4 * 512];

#define R2_LD(j) \
    f4v w0_##j, w1_##j, w2_##j, w3_##j; { \
        const float* p = U2 + (size_t)(kq * 32 + 4 * j) * 512 + cl; \
        w0_##j = (f4v){p[0],   p[512],       p[1024],       p[1536]}; \
        w1_##j = (f4v){p[128], p[512 + 128], p[1024 + 128], p[1536 + 128]}; \
        w2_##j = (f4v){p[256], p[512 + 256], p[1024 + 256], p[1536 + 256]}; \
        w3_##j = (f4v){p[384], p[512 + 384], p[1024 + 384], p[1536 + 384]}; }
    REP8(R2_LD)
#undef R2_LD
    // pin weights (r10: harmless here, keeps the gather rooted)
#define R2P(j) asm volatile("" : "+v"(w0_##j), "+v"(w1_##j), "+v"(w2_##j), "+v"(w3_##j));
    REP8(R2P)
#undef R2P

    const bool upd = (tid < H2);
    float cst = 0.0f;
    if (upd) {
        if (INIT) {
            hs[tid] = 0.0f;
        } else {
            hs[tid] = hbuf[(size_t)row * H2 + tid];
            cst = cbuf[(size_t)row * H2 + tid];
        }
    }
    // updater threads own all 4 gate columns {tid, tid+128, tid+256, tid+384}
    float zc0 = 0.f, zc1 = 0.f, zc2 = 0.f, zc3 = 0.f;
    if (upd) {
        const float* pz = zx + (size_t)row * 512 + tid;
        zc0 = pz[0]; zc1 = pz[128]; zc2 = pz[256]; zc3 = pz[384];
    }
    __syncthreads();

    for (int t = 0; t < tlen; ++t) {
        // prefetch next step's zx (updater threads only)
        float zn0 = 0.f, zn1 = 0.f, zn2 = 0.f, zn3 = 0.f;
        if (upd) {
            int tn = (t + 1 < tlen) ? t + 1 : t;
            const float* pz = zx + ((size_t)tn * BATCH + row) * 512 + tid;
            zn0 = pz[0]; zn1 = pz[128]; zn2 = pz[256]; zn3 = pz[384];
        }

        f4v s0 = {0.f, 0.f, 0.f, 0.f};
        f4v s1 = {0.f, 0.f, 0.f, 0.f};
        f4v s2 = {0.f, 0.f, 0.f, 0.f};
        f4v s3 = {0.f, 0.f, 0.f, 0.f};
#define R2_FMA(j) { f4v hv = *(const f4v*)&hs[kq * 32 + 4 * j]; \
        s0 += hv * w0_##j; s1 += hv * w1_##j; s2 += hv * w2_##j; s3 += hv * w3_##j; }
        REP8(R2_FMA)
#undef R2_FMA
        zp[kq * 512 + cl]       = hsum4_(s0);
        zp[kq * 512 + cl + 128] = hsum4_(s1);
        zp[kq * 512 + cl + 256] = hsum4_(s2);
        zp[kq * 512 + cl + 384] = hsum4_(s3);
        __syncthreads();   // barrier 1: zp complete; hs FMA-reads also complete

        if (upd) {
            float z0 = zc0 + (zp[tid]        + zp[512 + tid])
                           + (zp[1024 + tid] + zp[1536 + tid]);
            float z1 = zc1 + (zp[tid + 128]  + zp[512 + tid + 128])
                           + (zp[1024 + tid + 128] + zp[1536 + tid + 128]);
            float z2 = zc2 + (zp[tid + 256]  + zp[512 + tid + 256])
                           + (zp[1024 + tid + 256] + zp[1536 + tid + 256]);
            float z3 = zc3 + (zp[tid + 384]  + zp[512 + tid + 384])
                           + (zp[1024 + tid + 384] + zp[1536 + tid + 384]);
            float iv = sigmoidf_(z0);            // gate order i, f, g, o
            float fv = sigmoidf_(z1);
            float gv = fmaxf(z2, 0.0f);          // candidate: relu
            float ov = sigmoidf_(z3);
            cst = fv * cst + iv * gv;            // c = f*c + i*g
            hs[tid] = ov * fmaxf(cst, 0.0f);     // h = o*relu(c)
            zc0 = zn0; zc1 = zn1; zc2 = zn2; zc3 = zn3;
        }
        __syncthreads();   // barrier 2: hs(t+1) visible to all
    }

    if (upd) {
        float h = hs[tid];
        cbuf[(size_t)row * H2 + tid] = cst;
        hbuf[(size_t)row * H2 + tid] = h;
        if (LAST) h2out[(size_t)row * H2 + tid] = h;
    }
}

// =================== dense + softmax ===================
__global__ __launch_bounds__(64, 1)
void dense_softmax_kernel(const float* __restrict__ h2, const float* __restrict__ Wd,
                          const float* __restrict__ bd, float* __restrict__ out)
{
    const int b = blockIdx.x;
    const int k = threadIdx.x;
    __shared__ __align__(16) float hsm[H2];
    if (k < H2 / 4) ((f4v*)hsm)[k] = ((const f4v*)(h2 + (size_t)b * H2))[k];
    __syncthreads();

    float logit = -1e30f;
    if (k < NCLS) {
        float acc = bd[k];
#pragma unroll
        for (int d = 0; d < H2; ++d) acc += hsm[d] * Wd[d * NCLS + k];
        logit = acc;
    }
    float m = logit;
#pragma unroll
    for (int off = 32; off >= 1; off >>= 1) m = fmaxf(m, __shfl_xor(m, off, 64));
    float e = (k < NCLS) ? __expf(logit - m) : 0.0f;
    float s = e;
#pragma unroll
    for (int off = 32; off >= 1; off >>= 1) s += __shfl_xor(s, off, 64);
    if (k < NCLS) out[(size_t)b * NCLS + k] = e / s;
}

// =================== fallback (round-1) kernels ===================
__global__ __launch_bounds__(448, 1)
void lstm1_fb(const float* __restrict__ x, const float* __restrict__ W1,
              const float* __restrict__ U1, const float* __restrict__ b1,
              float* __restrict__ h1out)
{
    const int b = blockIdx.x;
    const int k = threadIdx.x;
    __shared__ __align__(16) float xs[IN_DIM];
    __shared__ __align__(16) float hs[H1];
    __shared__ __align__(16) float zs[4 * H1];
    float w1r[IN_DIM];
    float u1r[H1];
    float bias = 0.0f;
    if (k < 4 * H1) {
        bias = b1[k];
#pragma unroll
        for (int d = 0; d < IN_DIM; ++d) w1r[d] = W1[d * (4 * H1) + k];
#pragma unroll
        for (int j = 0; j < H1; ++j) u1r[j] = U1[j * (4 * H1) + k];
    }
    if (k < H1) hs[k] = 0.0f;
    if (k < IN_DIM / 4)
        ((float4*)xs)[k] = ((const float4*)(x + ((size_t)b * T_SEQ) * IN_DIM))[k];
    float c = 0.0f;
    __syncthreads();
    for (int t = 0; t < T_SEQ; ++t) {
        if (k < 4 * H1) {
            float acc0 = bias, acc1 = 0.f, acc2 = 0.f, acc3 = 0.f;
#pragma unroll
            for (int q = 0; q < IN_DIM / 4; ++q) {
                float4 xv = ((const float4*)xs)[q];
                acc0 += xv.x * w1r[4 * q]; acc1 += xv.y * w1r[4 * q + 1];
                acc2 += xv.z * w1r[4 * q + 2]; acc3 += xv.w * w1r[4 * q + 3];
            }
#pragma unroll
            for (int q = 0; q < H1 / 4; ++q) {
                float4 hv = ((const float4*)hs)[q];
                acc0 += hv.x * u1r[4 * q]; acc1 += hv.y * u1r[4 * q + 1];
                acc2 += hv.z * u1r[4 * q + 2]; acc3 += hv.w * u1r[4 * q + 3];
            }
            float zv = (acc0 + acc1) + (acc2 + acc3);
            zs[k] = (k >= 2 * H1 && k < 3 * H1) ? fmaxf(zv, 0.0f) : sigmoidf_(zv);
        }
        __syncthreads();
        if (k < H1) {
            float i = zs[k], f = zs[k + H1], g = zs[k + 2 * H1], o = zs[k + 3 * H1];
            c = f * c + i * g;
            float h = o * fmaxf(c, 0.0f);
            hs[k] = h;
            h1out[((size_t)t * BATCH + b) * H1 + k] = h;
        }
        int tn = t + 1;
        if (tn < T_SEQ && k < IN_DIM / 4)
            ((float4*)xs)[k] = ((const float4*)(x + ((size_t)b * T_SEQ + tn) * IN_DIM))[k];
        __syncthreads();
    }
}

__global__ __launch_bounds__(512, 1)
void lstm2_fb(const float* __restrict__ h1in, const float* __restrict__ W2,
              const float* __restrict__ U2, const float* __restrict__ b2,
              float* __restrict__ h2out)
{
    const int b = blockIdx.x;
    const int k = threadIdx.x;
    __shared__ __align__(16) float ps[H1];
    __shared__ __align__(16) float hs[H2];
    __shared__ __align__(16) float zs[4 * H2];
    float w2r[H1];
    float u2r[H2];
    float bias = b2[k];
#pragma unroll
    for (int j = 0; j < H1; ++j) w2r[j] = W2[j * (4 * H2) + k];
#pragma unroll
    for (int j = 0; j < H2; ++j) u2r[j] = U2[j * (4 * H2) + k];
    if (k < H2) hs[k] = 0.0f;
    if (k < H1 / 4)
        ((float4*)ps)[k] = ((const float4*)(h1in + (size_t)b * H1))[k];
    float c = 0.0f;
    float hlast = 0.0f;
    __syncthreads();
    for (int t = 0; t < T_SEQ; ++t) {
        float acc0 = bias, acc1 = 0.f, acc2 = 0.f, acc3 = 0.f;
#pragma unroll
        for (int q = 0; q < H1 / 4; ++q) {
            float4 pv = ((const float4*)ps)[q];
            acc0 += pv.x * w2r[4 * q]; acc1 += pv.y * w2r[4 * q + 1];
            acc2 += pv.z * w2r[4 * q + 2]; acc3 += pv.w * w2r[4 * q + 3];
        }
#pragma unroll
        for (int q = 0; q < H2 / 4; ++q) {
            float4 hv = ((const float4*)hs)[q];
            acc0 += hv.x * u2r[4 * q]; acc1 += hv.y * u2r[4 * q + 1];
            acc2 += hv.z * u2r[4 * q + 2]; acc3 += hv.w * u2r[4 * q + 3];
        }
        float zv = (acc0 + acc1) + (acc2 + acc3);
        zs[k] = (k >= 2 * H2 && k < 3 * H2) ? fmaxf(zv, 0.0f) : sigmoidf_(zv);
        __syncthreads();
        if (k < H2) {
            float i = zs[k], f = zs[k + H2], g = zs[k + 2 * H2], o = zs[k + 3 * H2];
            c = f * c + i * g;
            hlast = o * fmaxf(c, 0.0f);
            hs[k] = hlast;
        }
        int tn = t + 1;
        if (tn < T_SEQ && k < H1 / 4)
            ((float4*)ps)[k] = ((const float4*)(h1in + ((size_t)tn * BATCH + b) * H1))[k];
        __syncthreads();
    }
    if (k < H2) h2out[(size_t)b * H2 + k] = hlast;
}

extern "C" void kernel_launch(void* const* d_in, const int* in_sizes, int n_in,
                              void* d_out, int out_size, void* d_ws, size_t ws_size,
                              hipStream_t stream) {
    const float* x  = (const float*)d_in[0];
    const float* W1 = (const float*)d_in[1];
    const float* U1 = (const float*)d_in[2];
    const float* b1 = (const float*)d_in[3];
    const float* W2 = (const float*)d_in[4];
    const float* U2 = (const float*)d_in[5];
    const float* b2 = (const float*)d_in[6];
    const float* Wd = (const float*)d_in[7];
    const float* bd = (const float*)d_in[8];
    float* out = (float*)d_out;

    const size_t zx_elems = (size_t)T_SEQ * BATCH * 400;   // 52428800
    const size_t h1_elems = (size_t)T_SEQ * BATCH * H1;    // 13107200
    const size_t st_elems = (size_t)BATCH * H2;            // 65536
    const size_t need = (zx_elems + h1_elems + 3 * st_elems) * sizeof(float);  // 262.93 MB

    if (ws_size >= need) {
        float* zxbuf = (float*)d_ws;
        float* h1buf = zxbuf + zx_elems;
        float* cbuf  = h1buf + h1_elems;
        float* hbuf  = cbuf + st_elems;
        float* h2buf = hbuf + st_elems;
        const int TC = T_SEQ / 2;   // 128-step chunks

        // zx1 = x @ W1 + b1 -> [T][B][400]
        hipLaunchKernelGGL((proj_kernel<IN_DIM, 4 * H1, true>), dim3(1024, 4), dim3(256), 0, stream,
                           x, W1, b1, zxbuf);
        hipLaunchKernelGGL(rec1_kernel, dim3(BATCH), dim3(512), 0, stream,
                           zxbuf, U1, h1buf);
        // ---- layer 2, chunk A (t = 0..127): zx2 chunk overwrites zx1 region ----
        hipLaunchKernelGGL((proj_kernel<H1, 4 * H2, false>), dim3(512, 4), dim3(256), 0, stream,
                           h1buf, W2, b2, zxbuf);
        hipLaunchKernelGGL((rec2_chunk<true, false>), dim3(BATCH), dim3(512), 0, stream,
                           zxbuf, U2, cbuf, hbuf, h2buf, TC);
        // ---- layer 2, chunk B (t = 128..255) ----
        hipLaunchKernelGGL((proj_kernel<H1, 4 * H2, false>), dim3(512, 4), dim3(256), 0, stream,
                           h1buf + (size_t)TC * BATCH * H1, W2, b2, zxbuf);
        hipLaunchKernelGGL((rec2_chunk<false, true>), dim3(BATCH), dim3(512), 0, stream,
                           zxbuf, U2, cbuf, hbuf, h2buf, TC);

        hipLaunchKernelGGL(dense_softmax_kernel, dim3(BATCH), dim3(64), 0, stream,
                           h2buf, Wd, bd, out);
    } else {
        // fallback: round-1 fused kernels (needs ~52.7 MB)
        float* h1buf = (float*)d_ws;
        float* h2buf = h1buf + h1_elems;
        hipLaunchKernelGGL(lstm1_fb, dim3(BATCH), dim3(448), 0, stream, x, W1, U1, b1, h1buf);
        hipLaunchKernelGGL(lstm2_fb, dim3(BATCH), dim3(512), 0, stream, h1buf, W2, U2, b2, h2buf);
        hipLaunchKernelGGL(dense_softmax_kernel, dim3(BATCH), dim3(64), 0, stream, h2buf, Wd, bd, out);
    }
}